// Round 1
// baseline (2801.114 us; speedup 1.0000x reference)
//
#include <hip/hip_runtime.h>

// 4D conv net on MI355X. S=30, B=2, channels 1->10->10->1, kernel 3^4, pad 1,
// ReLU each layer. Symmetric: out = net(x,w) + net(x,w_perm) where w_perm
// swaps kernel dims (k1,k2)<->(k3,k4) -- algebraically identical to
// perm(net(perm(x))) and avoids physical transposes.

static constexpr int S  = 30;
static constexpr int S2 = S * S;            // 900
static constexpr long S4 = (long)S2 * S2;   // 810000
static constexpr int NB = 2;                // batch

// One block per (b, h1, w1). Block computes the full 30x30 (h2,t) plane for
// all COUT channels. For each of the 9 (k1,k2) offsets we stage the CIN
// haloed 32x32 input planes into LDS, then accumulate. Weight/bias reads are
// wave-uniform -> scalar loads.
template<int CIN, int COUT, bool ACCUM>
__global__ __launch_bounds__(256)
void conv4d_k(const float* __restrict__ in, const float* __restrict__ wgt,
              const float* __restrict__ bias, float* __restrict__ out, int swapk)
{
    __shared__ float plane[CIN][32][32];    // CIN=10 -> 40 KB
    const int w1 = blockIdx.x, h1 = blockIdx.y, b = blockIdx.z;
    const int tid = threadIdx.x;

    int h2i[4], t4[4], posv[4];
    bool pv[4];
    float acc[4][COUT];
#pragma unroll
    for (int i = 0; i < 4; ++i) {
        int p = tid + i * 256;
        pv[i] = (p < S2);
        if (!pv[i]) p = S2 - 1;             // clamp: keep LDS reads in-bounds
        posv[i] = p;
        h2i[i] = p / S;
        t4[i]  = p - h2i[i] * S;
#pragma unroll
        for (int co = 0; co < COUT; ++co) acc[i][co] = 0.f;
    }

    for (int k1 = 0; k1 < 3; ++k1) {
        const int g1 = h1 + k1 - 1;
        for (int k2 = 0; k2 < 3; ++k2) {
            const int g2 = w1 + k2 - 1;
            // zero padding: skip fully-out-of-range offset (block-uniform cond)
            if (g1 < 0 || g1 >= S || g2 < 0 || g2 >= S) continue;

            __syncthreads();  // previous compute done before restaging
            for (int idx = tid; idx < CIN * 1024; idx += 256) {
                const int c  = idx >> 10;
                const int r  = (idx >> 5) & 31;
                const int cl = idx & 31;
                const int hh = r - 1, tt = cl - 1;
                float v = 0.f;
                if ((unsigned)hh < (unsigned)S && (unsigned)tt < (unsigned)S)
                    v = in[((((long)b * CIN + c) * S + g1) * S + g2) * S2 + hh * S + tt];
                plane[c][r][cl] = v;
            }
            __syncthreads();

            for (int c = 0; c < CIN; ++c) {
#pragma unroll
                for (int k3 = 0; k3 < 3; ++k3) {
#pragma unroll
                    for (int k4 = 0; k4 < 3; ++k4) {
                        // branch 2 uses weights with (k1,k2)<->(k3,k4) swapped
                        const int i1 = swapk ? k3 : k1;
                        const int i2 = swapk ? k4 : k2;
                        const int i3 = swapk ? k1 : k3;
                        const int i4 = swapk ? k2 : k4;
                        float wv[COUT];
#pragma unroll
                        for (int co = 0; co < COUT; ++co)
                            wv[co] = wgt[((((co * CIN + c) * 3 + i1) * 3 + i2) * 3 + i3) * 3 + i4];
#pragma unroll
                        for (int i = 0; i < 4; ++i) {
                            const float v = plane[c][h2i[i] + k3][t4[i] + k4];
#pragma unroll
                            for (int co = 0; co < COUT; ++co)
                                acc[i][co] = fmaf(wv[co], v, acc[i][co]);
                        }
                    }
                }
            }
        }
    }

    float bv[COUT];
#pragma unroll
    for (int co = 0; co < COUT; ++co) bv[co] = bias[co];

#pragma unroll
    for (int i = 0; i < 4; ++i) {
        if (!pv[i]) continue;
#pragma unroll
        for (int co = 0; co < COUT; ++co) {
            float v = fmaxf(acc[i][co] + bv[co], 0.f);
            const long o = ((((long)b * COUT + co) * S + h1) * S + w1) * S2 + posv[i];
            if (ACCUM) out[o] += v; else out[o] = v;
        }
    }
}

extern "C" void kernel_launch(void* const* d_in, const int* in_sizes, int n_in,
                              void* d_out, int out_size, void* d_ws, size_t ws_size,
                              hipStream_t stream)
{
    const float* x   = (const float*)d_in[0];
    const float* w1p = (const float*)d_in[1];
    const float* b1p = (const float*)d_in[2];
    const float* w2p = (const float*)d_in[3];
    const float* b2p = (const float*)d_in[4];
    const float* w3p = (const float*)d_in[5];
    const float* b3p = (const float*)d_in[6];
    float* out = (float*)d_out;

    // Workspace: two ping-pong intermediates [B=2][10][30^4] fp32, 64.8 MB each.
    float* y1 = (float*)d_ws;
    float* y2 = y1 + (size_t)NB * 10 * S4;

    dim3 grid(S, S, NB), blk(256);
    for (int br = 0; br < 2; ++br) {
        conv4d_k<1, 10, false><<<grid, blk, 0, stream>>>(x,  w1p, b1p, y1, br);
        conv4d_k<10, 10, false><<<grid, blk, 0, stream>>>(y1, w2p, b2p, y2, br);
        if (br == 0)
            conv4d_k<10, 1, false><<<grid, blk, 0, stream>>>(y2, w3p, b3p, out, br);
        else
            conv4d_k<10, 1, true><<<grid, blk, 0, stream>>>(y2, w3p, b3p, out, br);
    }
}

// Round 2
// 916.249 us; speedup vs baseline: 3.0572x; 3.0572x over previous
//
#include <hip/hip_runtime.h>

// 4D conv net, MI355X. S=30, B=2, ch 1->10->10->1, kernel 3^4, pad 1, ReLU.
// Symmetric: out = net(x,w) + net(x,w_swap), w_swap has (k1,k2)<->(k3,k4).
// Layers 2,3: bf16 MFMA implicit GEMM (16x16x32). Layer 1: fp32 vector.
// Activations y1,y2 stored bf16 in workspace. B-fragments precomputed to ws.

static constexpr int S  = 30;
static constexpr int S2 = S * S;               // 900
static constexpr long S4 = (long)S2 * S2;      // 810000
static constexpr int NB = 2;

typedef __bf16 bf16x8 __attribute__((ext_vector_type(8)));
typedef float  f32x4  __attribute__((ext_vector_type(4)));
typedef unsigned int  u32;
typedef unsigned short u16;
static_assert(sizeof(bf16x8) == 16, "bf16x8 must be 16B");

static __device__ __forceinline__ u16 f2bf(float f) {
    u32 u = __builtin_bit_cast(u32, f);
    return (u16)((u + 0x7fffu + ((u >> 16) & 1u)) >> 16);
}

// ---------------------------------------------------------------------------
// B-fragment precompute. Table: [set(4)][k12(9)][f(6)][lane(64)] x uint4.
// set 0/1: layer2 br0/br1 (w2, COUT=10); set 2/3: layer3 br0/br1 (w3, COUT=1).
// K packing: f = 2*k3 + half. half0: k = k4*16 + c (k4 in {0,1}).
//            half1: k<16 -> k4=2, c=k&15; k>=16 -> zero pad.
// B[k][n]: lane = n + 16*q holds k = q*8+j, j=0..7.
__global__ __launch_bounds__(256) void fragprep_k(u32* __restrict__ ft,
    const float* __restrict__ w2, const float* __restrict__ w3)
{
    const int gid = blockIdx.x * 256 + threadIdx.x;   // 13824 total
    const int set = gid / 3456;
    int r = gid - set * 3456;
    const int k12 = r / 384;  r -= k12 * 384;
    const int f = r / 64;
    const int lane = r - f * 64;
    const int k1 = k12 / 3, k2 = k12 % 3;
    const int k3 = f >> 1, half = f & 1;
    const int n = lane & 15, q = lane >> 4;
    const int COUT = (set < 2) ? 10 : 1;
    const int swap = set & 1;
    const float* W = (set < 2) ? w2 : w3;

    u16 us[8];
#pragma unroll
    for (int j = 0; j < 8; ++j) {
        int k4, c;
        bool valid = true;
        if (!half) { k4 = q >> 1; c = (q & 1) * 8 + j; }
        else if (q < 2) { k4 = 2; c = (q & 1) * 8 + j; }
        else { k4 = 0; c = 0; valid = false; }
        valid = valid && (c < 10) && (n < COUT);
        float wv = 0.f;
        if (valid) {
            const int i1 = swap ? k3 : k1, i2 = swap ? k4 : k2;
            const int i3 = swap ? k1 : k3, i4 = swap ? k2 : k4;
            wv = W[(n * 10 + c) * 81 + i1 * 27 + i2 * 9 + i3 * 3 + i4];
        }
        us[j] = f2bf(wv);
    }
    u32* o = ft + (size_t)gid * 4;
    o[0] = (u32)us[0] | ((u32)us[1] << 16);
    o[1] = (u32)us[2] | ((u32)us[3] << 16);
    o[2] = (u32)us[4] | ((u32)us[5] << 16);
    o[3] = (u32)us[6] | ((u32)us[7] << 16);
}

// ---------------------------------------------------------------------------
// Layer 1: Cin=1, both branches merged (20 couts), fp32 vector, bf16 out.
__global__ __launch_bounds__(256, 4) void conv1_k(
    const float* __restrict__ x, const float* __restrict__ w1,
    const float* __restrict__ b1, u16* __restrict__ y1)
{
    __shared__ float P[32 * 33];                 // row-padded plane, 4.2 KB
    const int w1i = blockIdx.x, h1 = blockIdx.y, b = blockIdx.z;
    const int tid = threadIdx.x;

    int h2i[4], t4[4], posv[4];
    bool pv[4];
    float acc[4][20];
#pragma unroll
    for (int i = 0; i < 4; ++i) {
        int p = tid + i * 256;
        pv[i] = (p < S2);
        if (!pv[i]) p = S2 - 1;
        posv[i] = p; h2i[i] = p / S; t4[i] = p - h2i[i] * S;
#pragma unroll
        for (int co = 0; co < 20; ++co) acc[i][co] = 0.f;
    }
    for (int i = tid; i < 32 * 33; i += 256) P[i] = 0.f;

    for (int k12 = 0; k12 < 9; ++k12) {
        const int k1 = k12 / 3, k2 = k12 % 3;
        const int g1 = h1 + k1 - 1, g2 = w1i + k2 - 1;
        if (g1 < 0 || g1 >= S || g2 < 0 || g2 >= S) continue;
        __syncthreads();
        for (int idx = tid; idx < S2; idx += 256) {
            const int h = idx / S, t = idx - h * S;
            P[(h + 1) * 33 + (t + 1)] =
                x[(long)b * S4 + (long)(g1 * S + g2) * S2 + idx];
        }
        __syncthreads();
#pragma unroll
        for (int kk = 0; kk < 9; ++kk) {
            const int k3 = kk / 3, k4 = kk % 3;
            float wv[20];
#pragma unroll
            for (int co = 0; co < 20; ++co)
                wv[co] = (co < 10) ? w1[co * 81 + k12 * 9 + kk]
                                   : w1[(co - 10) * 81 + kk * 9 + k12];
#pragma unroll
            for (int i = 0; i < 4; ++i) {
                const float v = P[(h2i[i] + k3) * 33 + (t4[i] + k4)];
#pragma unroll
                for (int co = 0; co < 20; ++co)
                    acc[i][co] = fmaf(wv[co], v, acc[i][co]);
            }
        }
    }
#pragma unroll
    for (int i = 0; i < 4; ++i) {
        if (!pv[i]) continue;
#pragma unroll
        for (int co = 0; co < 20; ++co) {
            const int br = co / 10, c = co - br * 10;
            const float v = fmaxf(acc[i][co] + b1[c], 0.f);
            y1[(size_t)((br * NB + b) * 10 + c) * S4 +
               (long)(h1 * S + w1i) * S2 + posv[i]] = f2bf(v);
        }
    }
}

// ---------------------------------------------------------------------------
// MFMA conv: CIN=10, template COUT (10: bf16 out, 1: fp32 out +/- accum).
// Block = (w1, h1, b). LDS: RT[h'(32)][t'(33)][c(16)] bf16 = 33792 B.
// A-frag = one ds_read_b128 at uint4 idx (row*33+col)*2 + (q&1).
template<int COUT, bool ACCUM>
__global__ __launch_bounds__(256, 4) void convm_k(
    const u16* __restrict__ in, const u32* __restrict__ ftab,
    const float* __restrict__ bias, void* __restrict__ outp)
{
    __shared__ uint4 RT4[2112];
    const int w1i = blockIdx.x, h1 = blockIdx.y, b = blockIdx.z;
    const int tid = threadIdx.x;
    const int lane = tid & 63, wv = tid >> 6;
    const int m = lane & 15, q = lane >> 4;
    const int ch = q & 1, tq = q >> 1;
    const u16* inb = in + (size_t)b * 10 * S4;

    for (int i = tid; i < 2112; i += 256) RT4[i] = make_uint4(0, 0, 0, 0);

    f32x4 acc[15];
#pragma unroll
    for (int i = 0; i < 15; ++i) acc[i] = (f32x4){0.f, 0.f, 0.f, 0.f};

    u16* RTs = (u16*)RT4;
    for (int k12 = 0; k12 < 9; ++k12) {
        const int k1 = k12 / 3, k2 = k12 % 3;
        const int g1 = h1 + k1 - 1, g2 = w1i + k2 - 1;
        if (g1 < 0 || g1 >= S || g2 < 0 || g2 >= S) continue;
        __syncthreads();
        // fill valid cells: 10c x 30h x 15 t-pairs
        for (int it = tid; it < 4500; it += 256) {
            const int c = it / 450;
            int r = it - c * 450;
            const int h = r / 15, tp = r - h * 15;
            const u32 v = *(const u32*)(inb + (size_t)c * S4 +
                                        (long)(g1 * S + g2) * S2 + h * S + 2 * tp);
            const int base = ((h + 1) * 33 + (2 * tp + 1)) * 16 + c;
            RTs[base]      = (u16)(v & 0xffffu);
            RTs[base + 16] = (u16)(v >> 16);
        }
        __syncthreads();

        uint4 bf[6];
        {
            const uint4* ft4 = (const uint4*)ftab;
#pragma unroll
            for (int f = 0; f < 6; ++f)
                bf[f] = ft4[(k12 * 6 + f) * 64 + lane];
        }
#pragma unroll
        for (int i = 0; i < 15; ++i) {
            const int T = wv + 4 * i;
            const int h2 = T >> 1, t0 = (T & 1) * 14;
            const int rowbase = h2 * 33 + t0 + m;
            const int i0 = (rowbase + tq) * 2 + ch;   // half0 (k4 = tq)
            const int i2 = (rowbase + 2) * 2 + ch;    // half1 (k4 = 2)
#pragma unroll
            for (int k3 = 0; k3 < 3; ++k3) {
                const bf16x8 a0 = __builtin_bit_cast(bf16x8, RT4[i0 + 66 * k3]);
                const bf16x8 b0 = __builtin_bit_cast(bf16x8, bf[2 * k3]);
                acc[i] = __builtin_amdgcn_mfma_f32_16x16x32_bf16(a0, b0, acc[i], 0, 0, 0);
                const bf16x8 a1 = __builtin_bit_cast(bf16x8, RT4[i2 + 66 * k3]);
                const bf16x8 b1 = __builtin_bit_cast(bf16x8, bf[2 * k3 + 1]);
                acc[i] = __builtin_amdgcn_mfma_f32_16x16x32_bf16(a1, b1, acc[i], 0, 0, 0);
            }
        }
    }

    // Epilogue. D: lane holds C[mrow = q*4+r][n = lane&15].
    const int n = lane & 15;
    const float bv = (n < COUT) ? bias[n] : 0.f;
    const long plane = (long)(h1 * S + w1i) * S2;
#pragma unroll
    for (int i = 0; i < 15; ++i) {
        const int T = wv + 4 * i;
        const int h2 = T >> 1, t0 = (T & 1) * 14;
#pragma unroll
        for (int r = 0; r < 4; ++r) {
            const int mrow = 4 * q + r;
            if ((T & 1) && mrow < 2) continue;       // skip overlapped t=14,15
            if (n >= COUT) continue;
            const int t = t0 + mrow;
            const float v = fmaxf(acc[i][r] + bv, 0.f);
            if (COUT == 10) {
                ((u16*)outp)[(size_t)(b * 10 + n) * S4 + plane + h2 * S + t] = f2bf(v);
            } else {
                float* o = (float*)outp + (size_t)b * S4 + plane + h2 * S + t;
                if (ACCUM) *o += v; else *o = v;
            }
        }
    }
}

// ---------------------------------------------------------------------------
extern "C" void kernel_launch(void* const* d_in, const int* in_sizes, int n_in,
                              void* d_out, int out_size, void* d_ws, size_t ws_size,
                              hipStream_t stream)
{
    const float* x   = (const float*)d_in[0];
    const float* w1p = (const float*)d_in[1];
    const float* b1p = (const float*)d_in[2];
    const float* w2p = (const float*)d_in[3];
    const float* b2p = (const float*)d_in[4];
    const float* w3p = (const float*)d_in[5];
    const float* b3p = (const float*)d_in[6];
    float* out = (float*)d_out;

    // ws layout: fragtab (221184 B) | y1 bf16 [2br][2b][10][S4] | y2 bf16 [2b][10][S4]
    u32* ft  = (u32*)d_ws;
    u16* y1  = (u16*)((char*)d_ws + 13824 * 16);
    u16* y2  = (u16*)((char*)y1 + (size_t)2 * NB * 10 * S4 * 2);

    fragprep_k<<<54, 256, 0, stream>>>(ft, w2p, w3p);

    dim3 grid(S, S, NB), blk(256);
    conv1_k<<<grid, blk, 0, stream>>>(x, w1p, b1p, y1);

    for (int br = 0; br < 2; ++br) {
        const u16* in1 = y1 + (size_t)br * NB * 10 * S4;
        const u32* ft2 = ft + (size_t)br * 3456 * 4;
        const u32* ft3 = ft + (size_t)(2 + br) * 3456 * 4;
        convm_k<10, false><<<grid, blk, 0, stream>>>(in1, ft2, b2p, (void*)y2);
        if (br == 0)
            convm_k<1, false><<<grid, blk, 0, stream>>>(y2, ft3, b3p, (void*)out);
        else
            convm_k<1, true><<<grid, blk, 0, stream>>>(y2, ft3, b3p, (void*)out);
    }
}

// Round 4
// 663.376 us; speedup vs baseline: 4.2225x; 1.3812x over previous
//
#include <hip/hip_runtime.h>

// 4D conv net, MI355X. S=30, B=2, ch 1->10->10->1, kernel 3^4, pad 1, ReLU.
// out = net(x,w) + net(x,w_swap), w_swap has (k1,k2)<->(k3,k4).
// Layers 2,3: bf16 MFMA implicit GEMM, K=32 packed as (k4,c) 30/32 dense.
// LDS rows (h',t') of 20 dwords (80 B) with 16B-chunk rotation by t' mod 5
// to kill staging bank conflicts; k3-chained A-fragment reuse; register
// prefetch of next-k12 globals + B-frags.
// R4 fix: fragtab is 6912 uint4 = 110592 B (R3 placed y1 at +27648 B,
// overlapping the table -> garbage weights).

static constexpr int S  = 30;
static constexpr int S2 = 900;
static constexpr long S4 = 810000;
static constexpr int NB = 2;

typedef __bf16 bf16x8 __attribute__((ext_vector_type(8)));
typedef float  f32x4  __attribute__((ext_vector_type(4)));
typedef unsigned int  u32;
typedef unsigned short u16;

static __device__ __forceinline__ u16 f2bf(float f) {
    u32 u = __builtin_bit_cast(u32, f);
    return (u16)((u + 0x7fffu + ((u >> 16) & 1u)) >> 16);
}
static __device__ __forceinline__ int mod5(int t) { return t - 5 * ((t * 52) >> 8); } // valid t<32

// ---------------------------------------------------------------------------
// B-fragment table: [set(4)][k12(9)][k3(3)][lane(64)] uint4.
// set 0/1: layer2 br0/br1 (w2, COUT=10); set 2/3: layer3 br0/br1 (w3, COUT=1).
// K-slot s = 10*k4 + c (s<30; 30,31 zero). Lane = n + 16q holds k = q*8+j.
__global__ __launch_bounds__(256) void fragprep_k(u32* __restrict__ ft,
    const float* __restrict__ w2, const float* __restrict__ w3)
{
    const int gid = blockIdx.x * 256 + threadIdx.x;   // 6912 total
    const int lane = gid & 63;
    int r = gid >> 6;
    const int k3 = r % 3; r /= 3;
    const int k12 = r % 9; const int set = r / 9;
    const int k1 = k12 / 3, k2 = k12 % 3;
    const int n = lane & 15, q = lane >> 4;
    const int COUT = (set < 2) ? 10 : 1;
    const int swap = set & 1;
    const float* W = (set < 2) ? w2 : w3;

    u16 us[8];
#pragma unroll
    for (int j = 0; j < 8; ++j) {
        const int k = q * 8 + j;
        float wv = 0.f;
        if (k < 30 && n < COUT) {
            const int k4 = (k < 10) ? 0 : ((k < 20) ? 1 : 2);
            const int c  = k - 10 * k4;
            const int i1 = swap ? k3 : k1, i2 = swap ? k4 : k2;
            const int i3 = swap ? k1 : k3, i4 = swap ? k2 : k4;
            wv = W[(n * 10 + c) * 81 + ((i1 * 3 + i2) * 3 + i3) * 3 + i4];
        }
        us[j] = f2bf(wv);
    }
    u32* o = ft + (size_t)gid * 4;
    o[0] = (u32)us[0] | ((u32)us[1] << 16);
    o[1] = (u32)us[2] | ((u32)us[3] << 16);
    o[2] = (u32)us[4] | ((u32)us[5] << 16);
    o[3] = (u32)us[6] | ((u32)us[7] << 16);
}

// ---------------------------------------------------------------------------
// Layer 1: Cin=1, both branches merged (20 couts), fp32 vector, bf16 out.
__global__ __launch_bounds__(256, 4) void conv1_k(
    const float* __restrict__ x, const float* __restrict__ w1,
    const float* __restrict__ b1, u16* __restrict__ y1)
{
    __shared__ float P[32 * 33];
    const int w1i = blockIdx.x, h1 = blockIdx.y, b = blockIdx.z;
    const int tid = threadIdx.x;

    int h2i[4], t4[4], posv[4];
    bool pv[4];
    float acc[4][20];
#pragma unroll
    for (int i = 0; i < 4; ++i) {
        int p = tid + i * 256;
        pv[i] = (p < S2);
        if (!pv[i]) p = S2 - 1;
        posv[i] = p; h2i[i] = p / S; t4[i] = p - h2i[i] * S;
#pragma unroll
        for (int co = 0; co < 20; ++co) acc[i][co] = 0.f;
    }
    for (int i = tid; i < 32 * 33; i += 256) P[i] = 0.f;

    for (int k12 = 0; k12 < 9; ++k12) {
        const int k1 = k12 / 3, k2 = k12 % 3;
        const int g1 = h1 + k1 - 1, g2 = w1i + k2 - 1;
        if (g1 < 0 || g1 >= S || g2 < 0 || g2 >= S) continue;
        __syncthreads();
        for (int idx = tid; idx < S2; idx += 256) {
            const int h = idx / S, t = idx - h * S;
            P[(h + 1) * 33 + (t + 1)] =
                x[(long)b * S4 + (long)(g1 * S + g2) * S2 + idx];
        }
        __syncthreads();
#pragma unroll
        for (int kk = 0; kk < 9; ++kk) {
            const int k3 = kk / 3, k4 = kk % 3;
            float wv[20];
#pragma unroll
            for (int co = 0; co < 20; ++co)
                wv[co] = (co < 10) ? w1[co * 81 + k12 * 9 + kk]
                                   : w1[(co - 10) * 81 + kk * 9 + k12];
#pragma unroll
            for (int i = 0; i < 4; ++i) {
                const float v = P[(h2i[i] + k3) * 33 + (t4[i] + k4)];
#pragma unroll
                for (int co = 0; co < 20; ++co)
                    acc[i][co] = fmaf(wv[co], v, acc[i][co]);
            }
        }
    }
#pragma unroll
    for (int i = 0; i < 4; ++i) {
        if (!pv[i]) continue;
#pragma unroll
        for (int co = 0; co < 20; ++co) {
            const int br = co / 10, c = co - br * 10;
            const float v = fmaxf(acc[i][co] + b1[c], 0.f);
            y1[(size_t)((br * NB + b) * 10 + c) * S4 +
               (long)(h1 * S + w1i) * S2 + posv[i]] = f2bf(v);
        }
    }
}

// ---------------------------------------------------------------------------
// MFMA conv, K-packed. LDS: [h'(32)][t'(30)] rows of 20 dwords (80 B).
// Logical K dword d (0..14): 16B-chunk (d>>2) rotated by t' mod 5 over the
// row's 5 chunks; dword-in-chunk d&3. Slots 30,31 + halo rows stay zero.
template<int COUT, bool ACCUM>
__global__ __launch_bounds__(256, 2) void convm_k(
    const u16* __restrict__ in, const u32* __restrict__ ftab,
    const float* __restrict__ bias, void* __restrict__ outp)
{
    __shared__ u32 RT[19204];            // 32*30*20 dwords + dump dword @19200
    const int w1i = blockIdx.x, h1 = blockIdx.y, b = blockIdx.z;
    const int tid = threadIdx.x;
    const int lane = tid & 63, wv = tid >> 6;
    const int m = lane & 15, q = lane >> 4;
    const u16* inb = in + (size_t)b * 10 * S4;

    {
        const uint4 z = make_uint4(0, 0, 0, 0);
        for (int i = tid; i < 4801; i += 256) ((uint4*)RT)[i] = z;
    }

    f32x4 acc[15];
#pragma unroll
    for (int i = 0; i < 15; ++i) acc[i] = (f32x4){0.f, 0.f, 0.f, 0.f};

    // valid (k1,k2) list: plane offset (u16 elems, <2^20) | k12<<20
    int kl[9], nk = 0;
    for (int k12 = 0; k12 < 9; ++k12) {
        const int g1 = h1 + k12 / 3 - 1, g2 = w1i + k12 % 3 - 1;
        if (g1 >= 0 && g1 < S && g2 >= 0 && g2 < S)
            kl[nk++] = ((g1 * S + g2) * S2) | (k12 << 20);
    }

    // staging invariants: thread covers it = tid+256j over (cp5, h30, tp15)
    int goff[9], wad[9][6];
#pragma unroll
    for (int j = 0; j < 9; ++j) {
        int it = tid + 256 * j; if (it > 2249) it = 2249;
        const int cp = it / 450; int r2 = it - 450 * cp;
        const int h = r2 / 15, tp = r2 - 15 * h;
        goff[j] = 2 * cp * (int)S4 + h * S + 2 * tp;
        const int hbase = (h + 1) * 600;
#pragma unroll
        for (int sel = 0; sel < 2; ++sel)
#pragma unroll
            for (int k4 = 0; k4 < 3; ++k4) {
                const int tpr = 2 * tp + sel + 1 - k4;     // t'
                const int widx = sel * 3 + k4;
                if (tpr < 0 || tpr >= S) { wad[j][widx] = 19200; continue; }
                const int d = 5 * k4 + cp;
                int ph = (d >> 2) + mod5(tpr); if (ph >= 5) ph -= 5;
                wad[j][widx] = hbase + tpr * 20 + ph * 4 + (d & 3);
            }
    }

    // read invariants: wave's tile i has h2 = 2i+h0, t0 fixed; A row t' = t0+m
    const int t0 = (wv & 1) * 14;
    const int h0 = wv >> 1;
    const int tpr_r = t0 + m;
    int phq = q + mod5(tpr_r); if (phq >= 5) phq -= 5;
    const int rdbase = tpr_r * 80 + phq * 16 + h0 * 2400;  // bytes

    // prefetch k12[0] globals + B-frags
    u32 pA[9], pB[9];
    {
        const int plane = kl[0] & 0xfffff;
#pragma unroll
        for (int j = 0; j < 9; ++j) {
            pA[j] = *(const u32*)(inb + plane + goff[j]);
            pB[j] = *(const u32*)(inb + plane + goff[j] + S4);
        }
    }
    uint4 bfr[3];
    {
        const int k12 = kl[0] >> 20;
#pragma unroll
        for (int f = 0; f < 3; ++f)
            bfr[f] = ((const uint4*)ftab)[(k12 * 3 + f) * 64 + lane];
    }

    for (int ki = 0; ki < nk; ++ki) {
        __syncthreads();                 // prev consumers done
        // issue next-k12 B loads (consumed next iter -> fully hidden)
        uint4 bnx[3];
        {
            const int k12n = kl[(ki + 1 < nk) ? (ki + 1) : ki] >> 20;
#pragma unroll
            for (int f = 0; f < 3; ++f)
                bnx[f] = ((const uint4*)ftab)[(k12n * 3 + f) * 64 + lane];
        }
        // write staging from prefetched regs (addresses precomputed)
#pragma unroll
        for (int j = 0; j < 9; ++j) {
            const u32 a = pA[j], bb = pB[j];
            const u32 w0 = (a & 0xffffu) | (bb << 16);
            const u32 w1 = (a >> 16) | (bb & 0xffff0000u);
            RT[wad[j][0]] = w0; RT[wad[j][1]] = w0; RT[wad[j][2]] = w0;
            RT[wad[j][3]] = w1; RT[wad[j][4]] = w1; RT[wad[j][5]] = w1;
        }
        __syncthreads();                 // LDS ready
        // prefetch next-k12 globals (hidden under compute)
        if (ki + 1 < nk) {
            const int plane = kl[ki + 1] & 0xfffff;
#pragma unroll
            for (int j = 0; j < 9; ++j) {
                pA[j] = *(const u32*)(inb + plane + goff[j]);
                pB[j] = *(const u32*)(inb + plane + goff[j] + S4);
            }
        }
        // compute: k3-chained fragments, 2 fresh reads + 3 MFMAs per tile
        const char* bp = (const char*)RT + rdbase;
        bf16x8 a0 = __builtin_bit_cast(bf16x8, *(const uint4*)bp);
        const bf16x8 B0 = __builtin_bit_cast(bf16x8, bfr[0]);
        const bf16x8 B1 = __builtin_bit_cast(bf16x8, bfr[1]);
        const bf16x8 B2 = __builtin_bit_cast(bf16x8, bfr[2]);
#pragma unroll
        for (int i = 0; i < 15; ++i) {
            const bf16x8 a1 = __builtin_bit_cast(bf16x8, *(const uint4*)(bp + 2400));
            const bf16x8 a2 = __builtin_bit_cast(bf16x8, *(const uint4*)(bp + 4800));
            acc[i] = __builtin_amdgcn_mfma_f32_16x16x32_bf16(a0, B0, acc[i], 0, 0, 0);
            acc[i] = __builtin_amdgcn_mfma_f32_16x16x32_bf16(a1, B1, acc[i], 0, 0, 0);
            acc[i] = __builtin_amdgcn_mfma_f32_16x16x32_bf16(a2, B2, acc[i], 0, 0, 0);
            a0 = a2;
            bp += 4800;
        }
        bfr[0] = bnx[0]; bfr[1] = bnx[1]; bfr[2] = bnx[2];
    }

    // epilogue: C lane holds row (4q+r), col n
    const int n = lane & 15;
    const float bv = (n < COUT) ? bias[n] : 0.f;
    const long plane = (long)(h1 * S + w1i) * S2;
#pragma unroll
    for (int i = 0; i < 15; ++i) {
        const int h2 = 2 * i + h0;
#pragma unroll
        for (int r = 0; r < 4; ++r) {
            const int mrow = 4 * q + r;
            if (t0 && mrow < 2) continue;        // t=14,15 owned by t0=0 tiles
            if (n >= COUT) continue;
            const int t = t0 + mrow;
            const float v = fmaxf(acc[i][r] + bv, 0.f);
            if (COUT == 10) {
                ((u16*)outp)[(size_t)(b * 10 + n) * S4 + plane + h2 * S + t] = f2bf(v);
            } else {
                float* o = (float*)outp + (size_t)b * S4 + plane + h2 * S + t;
                if (ACCUM) *o += v; else *o = v;
            }
        }
    }
}

// ---------------------------------------------------------------------------
extern "C" void kernel_launch(void* const* d_in, const int* in_sizes, int n_in,
                              void* d_out, int out_size, void* d_ws, size_t ws_size,
                              hipStream_t stream)
{
    const float* x   = (const float*)d_in[0];
    const float* w1p = (const float*)d_in[1];
    const float* b1p = (const float*)d_in[2];
    const float* w2p = (const float*)d_in[3];
    const float* b2p = (const float*)d_in[4];
    const float* w3p = (const float*)d_in[5];
    const float* b3p = (const float*)d_in[6];
    float* out = (float*)d_out;

    // ws: fragtab 6912 uint4 = 110592 B | y1 bf16 [2br][2b][10][S4] | y2 bf16 [2b][10][S4]
    u32* ft = (u32*)d_ws;
    u16* y1 = (u16*)((char*)d_ws + 110592);
    u16* y2 = (u16*)((char*)y1 + (size_t)2 * NB * 10 * S4 * 2);

    fragprep_k<<<27, 256, 0, stream>>>(ft, w2p, w3p);

    dim3 grid(S, S, NB), blk(256);
    conv1_k<<<grid, blk, 0, stream>>>(x, w1p, b1p, y1);

    for (int br = 0; br < 2; ++br) {
        const u16* in1 = y1 + (size_t)br * NB * 10 * S4;
        const u32* ft2 = ft + (size_t)br * 6912;
        const u32* ft3 = ft + (size_t)(2 + br) * 6912;
        convm_k<10, false><<<grid, blk, 0, stream>>>(in1, ft2, b2p, (void*)y2);
        if (br == 0)
            convm_k<1, false><<<grid, blk, 0, stream>>>(y2, ft3, b3p, (void*)out);
        else
            convm_k<1, true><<<grid, blk, 0, stream>>>(y2, ft3, b3p, (void*)out);
    }
}